// Round 1
// baseline (126.205 us; speedup 1.0000x reference)
//
#include <hip/hip_runtime.h>
#include <hip/hip_bf16.h>

typedef float f4v __attribute__((ext_vector_type(4)));
typedef float f32x4 __attribute__((ext_vector_type(4)));
typedef __bf16 bf16x8 __attribute__((ext_vector_type(8)));

#define GLDS16(gsrc, ldst)                                                  \
  __builtin_amdgcn_global_load_lds(                                         \
      (const __attribute__((address_space(1))) unsigned int*)(gsrc),        \
      (__attribute__((address_space(3))) unsigned int*)(ldst), 16, 0, 0)

__device__ __forceinline__ unsigned pack2bf(float lo, float hi) {
  unsigned short ua = __builtin_bit_cast(unsigned short, (__bf16)lo);
  unsigned short ub = __builtin_bit_cast(unsigned short, (__bf16)hi);
  return (unsigned)ua | ((unsigned)ub << 16);
}

// ---------------- kernel 1: modulation MLP -> s [16][512] (f32, ws) -------
__global__ __launch_bounds__(256) void mlp_kernel(
    const float* __restrict__ t,
    const float* __restrict__ W1, const float* __restrict__ b1,
    const float* __restrict__ W2, const float* __restrict__ b2,
    const float* __restrict__ W3, const float* __restrict__ b3,
    float* __restrict__ s_out) {
  __shared__ float tt[256];
  __shared__ float hh[256];
  const int b = blockIdx.x;
  const int tid = threadIdx.x;
  tt[tid] = t[b * 256 + tid];
  __syncthreads();
  // layer 1: h1 = silu(t @ W1^T + b1)
  float acc = b1[tid];
  {
    const f4v* wrow = (const f4v*)(W1 + tid * 256);
    #pragma unroll 16
    for (int k = 0; k < 64; ++k) {
      f4v wv = wrow[k];
      acc += wv[0] * tt[4 * k] + wv[1] * tt[4 * k + 1] +
             wv[2] * tt[4 * k + 2] + wv[3] * tt[4 * k + 3];
    }
  }
  float h = acc / (1.0f + expf(-acc));
  __syncthreads();
  hh[tid] = h;
  __syncthreads();
  // layer 2: h2 = silu(h1 @ W2^T + b2)
  acc = b2[tid];
  {
    const f4v* wrow = (const f4v*)(W2 + tid * 256);
    #pragma unroll 16
    for (int k = 0; k < 64; ++k) {
      f4v wv = wrow[k];
      acc += wv[0] * hh[4 * k] + wv[1] * hh[4 * k + 1] +
             wv[2] * hh[4 * k + 2] + wv[3] * hh[4 * k + 3];
    }
  }
  h = acc / (1.0f + expf(-acc));
  __syncthreads();
  tt[tid] = h;  // reuse tt as h2
  __syncthreads();
  // layer 3: s = h2 @ W3^T + b3 + 1
  #pragma unroll
  for (int rep = 0; rep < 2; ++rep) {
    const int o = rep * 256 + tid;
    float a3 = b3[o];
    const f4v* wrow = (const f4v*)(W3 + o * 256);
    #pragma unroll 16
    for (int k = 0; k < 64; ++k) {
      f4v wv = wrow[k];
      a3 += wv[0] * tt[4 * k] + wv[1] * tt[4 * k + 1] +
            wv[2] * tt[4 * k + 2] + wv[3] * tt[4 * k + 3];
    }
    s_out[b * 512 + o] = a3 + 1.0f;
  }
}

// ---------------- kernel 2: demod + bw (bf16) [16][512][512] --------------
// one wave per (b, o) row
__global__ __launch_bounds__(256) void modw_kernel(
    const float* __restrict__ weight, const float* __restrict__ s_in,
    unsigned short* __restrict__ bwq) {
  const int tid = threadIdx.x;
  const int wid = (blockIdx.x << 2) | (tid >> 6);  // 0..8191
  const int b = wid >> 9;
  const int o = wid & 511;
  const int lane = tid & 63;
  const f4v* wp = (const f4v*)(weight + o * 512 + lane * 8);
  const f4v* sp = (const f4v*)(s_in + b * 512 + lane * 8);
  f4v w0 = wp[0], w1 = wp[1];
  f4v s0 = sp[0], s1 = sp[1];
  float p[8];
  p[0] = w0[0] * s0[0]; p[1] = w0[1] * s0[1];
  p[2] = w0[2] * s0[2]; p[3] = w0[3] * s0[3];
  p[4] = w1[0] * s1[0]; p[5] = w1[1] * s1[1];
  p[6] = w1[2] * s1[2]; p[7] = w1[3] * s1[3];
  float ss = 0.0f;
  #pragma unroll
  for (int i = 0; i < 8; ++i) ss += p[i] * p[i];
  #pragma unroll
  for (int off = 32; off; off >>= 1) ss += __shfl_xor(ss, off);
  const float d = rsqrtf(ss + 1e-8f);
  uint4 outw;
  outw.x = pack2bf(p[0] * d, p[1] * d);
  outw.y = pack2bf(p[2] * d, p[3] * d);
  outw.z = pack2bf(p[4] * d, p[5] * d);
  outw.w = pack2bf(p[6] * d, p[7] * d);
  *(uint4*)(bwq + ((size_t)(b * 512 + o)) * 512 + lane * 8) = outw;
}

// ---------------- kernel 3: batched GEMM out[b] = bw[b] @ x[b] ------------
// A = bw [512][512] bf16 (k-contig), B = x [512][4096] f32 (transposed into
// LDS [n][k] bf16 on the fly). 128x128 tile, BK=32, 4 waves, 16x16x32 MFMA.
__global__ __launch_bounds__(256, 2) void gemm_kernel(
    const float* __restrict__ x, const unsigned short* __restrict__ bwq,
    float* __restrict__ out) {
  __shared__ __align__(16) unsigned short As[2][128 * 32];  // [buf][m][k]
  __shared__ __align__(16) unsigned short Bs[128 * 32];     // [n][k] swizzled

  const int bid = blockIdx.x;
  // XCD swizzle (2048 blocks, 8 XCDs, contiguous 256-chunks per XCD).
  const int swz = ((bid & 7) << 8) | (bid >> 3);
  const int mt = swz & 3;           // m-tile innermost: 4 blocks share x panel
  const int nt = (swz >> 2) & 31;
  const int bb = swz >> 7;

  const int tid = threadIdx.x;
  const int lane = tid & 63;
  const int wv = tid >> 6;
  const int wr = wv >> 1, wc = wv & 1;

  const unsigned short* abase = bwq + ((size_t)(bb * 512 + mt * 128)) * 512;
  const float* xbase = x + ((size_t)bb * 512) * 4096 + nt * 128;

  // B staging: thread covers i-quad pq (4 rows) x l-chunk lc (4 cols)
  const int pq = tid >> 5;  // 0..7
  const int lc = tid & 31;  // 0..31
  const float* xp = xbase + (size_t)(pq * 4) * 4096 + lc * 4;
  const int sw_w = (lc & 3) << 4;  // write-side XOR swizzle ((n>>2)&3)<<4
  char* BsB = (char*)Bs;

  // A staging granules
  const int g0 = tid, g1 = 256 + tid;
  const unsigned short* asrc0 = abase + (g0 >> 2) * 512 + (g0 & 3) * 8;
  const unsigned short* asrc1 = abase + (g1 >> 2) * 512 + (g1 & 3) * 8;

  // fragment read addressing
  const int arow = wr * 64 + (lane & 15);       // + mi*16
  const int kgo = (lane >> 4) * 8;              // ushort offset within row
  const int nrow0 = wc * 64 + (lane & 15);      // + ni*16
  const int sb = (nrow0 >> 2) & 3;              // read-side swizzle
  const int bByte = nrow0 * 64 + (((lane >> 4) ^ sb) << 4);  // + ni*1024

  f32x4 acc[4][4] = {};

  // prologue: stage A[0] (k0=0), load x regs (it=0)
  GLDS16(asrc0, &As[0][g0 * 8]);
  GLDS16(asrc1, &As[0][g1 * 8]);
  f4v v0 = *(const f4v*)(xp);
  f4v v1 = *(const f4v*)(xp + 4096);
  f4v v2 = *(const f4v*)(xp + 8192);
  f4v v3 = *(const f4v*)(xp + 12288);
  f4v t0, t1, t2, t3;

  for (int it = 0; it < 16; ++it) {
    const int cur = it & 1;
    // write B tile (bf16, transposed [n][k], b64 writes, swizzled)
    {
      float r0[4] = {v0[0], v0[1], v0[2], v0[3]};
      float r1[4] = {v1[0], v1[1], v1[2], v1[3]};
      float r2[4] = {v2[0], v2[1], v2[2], v2[3]};
      float r3[4] = {v3[0], v3[1], v3[2], v3[3]};
      #pragma unroll
      for (int j = 0; j < 4; ++j) {
        uint2 val;
        val.x = pack2bf(r0[j], r1[j]);
        val.y = pack2bf(r2[j], r3[j]);
        const int n = (lc << 2) + j;
        *(uint2*)(BsB + n * 64 + ((pq * 8) ^ sw_w)) = val;
      }
    }
    __syncthreads();  // A[cur] DMA + B writes visible

    // prefetch next iter (overlaps MFMA)
    if (it < 15) {
      const int k0n = (it + 1) << 5;
      const unsigned short* an0 = asrc0 + k0n;
      const unsigned short* an1 = asrc1 + k0n;
      GLDS16(an0, &As[cur ^ 1][g0 * 8]);
      GLDS16(an1, &As[cur ^ 1][g1 * 8]);
      const float* xn = xp + (size_t)k0n * 4096;
      t0 = *(const f4v*)(xn);
      t1 = *(const f4v*)(xn + 4096);
      t2 = *(const f4v*)(xn + 8192);
      t3 = *(const f4v*)(xn + 12288);
    }

    // compute
    {
      const unsigned short* ab = &As[cur][0];
      bf16x8 a0 = *(const bf16x8*)(ab + arow * 32 + kgo);
      bf16x8 a1 = *(const bf16x8*)(ab + arow * 32 + 512 + kgo);
      bf16x8 a2 = *(const bf16x8*)(ab + arow * 32 + 1024 + kgo);
      bf16x8 a3 = *(const bf16x8*)(ab + arow * 32 + 1536 + kgo);
      bf16x8 bf0 = *(const bf16x8*)(BsB + bByte);
      bf16x8 bf1 = *(const bf16x8*)(BsB + bByte + 1024);
      bf16x8 bf2 = *(const bf16x8*)(BsB + bByte + 2048);
      bf16x8 bf3 = *(const bf16x8*)(BsB + bByte + 3072);
      acc[0][0] = __builtin_amdgcn_mfma_f32_16x16x32_bf16(a0, bf0, acc[0][0], 0, 0, 0);
      acc[0][1] = __builtin_amdgcn_mfma_f32_16x16x32_bf16(a0, bf1, acc[0][1], 0, 0, 0);
      acc[0][2] = __builtin_amdgcn_mfma_f32_16x16x32_bf16(a0, bf2, acc[0][2], 0, 0, 0);
      acc[0][3] = __builtin_amdgcn_mfma_f32_16x16x32_bf16(a0, bf3, acc[0][3], 0, 0, 0);
      acc[1][0] = __builtin_amdgcn_mfma_f32_16x16x32_bf16(a1, bf0, acc[1][0], 0, 0, 0);
      acc[1][1] = __builtin_amdgcn_mfma_f32_16x16x32_bf16(a1, bf1, acc[1][1], 0, 0, 0);
      acc[1][2] = __builtin_amdgcn_mfma_f32_16x16x32_bf16(a1, bf2, acc[1][2], 0, 0, 0);
      acc[1][3] = __builtin_amdgcn_mfma_f32_16x16x32_bf16(a1, bf3, acc[1][3], 0, 0, 0);
      acc[2][0] = __builtin_amdgcn_mfma_f32_16x16x32_bf16(a2, bf0, acc[2][0], 0, 0, 0);
      acc[2][1] = __builtin_amdgcn_mfma_f32_16x16x32_bf16(a2, bf1, acc[2][1], 0, 0, 0);
      acc[2][2] = __builtin_amdgcn_mfma_f32_16x16x32_bf16(a2, bf2, acc[2][2], 0, 0, 0);
      acc[2][3] = __builtin_amdgcn_mfma_f32_16x16x32_bf16(a2, bf3, acc[2][3], 0, 0, 0);
      acc[3][0] = __builtin_amdgcn_mfma_f32_16x16x32_bf16(a3, bf0, acc[3][0], 0, 0, 0);
      acc[3][1] = __builtin_amdgcn_mfma_f32_16x16x32_bf16(a3, bf1, acc[3][1], 0, 0, 0);
      acc[3][2] = __builtin_amdgcn_mfma_f32_16x16x32_bf16(a3, bf2, acc[3][2], 0, 0, 0);
      acc[3][3] = __builtin_amdgcn_mfma_f32_16x16x32_bf16(a3, bf3, acc[3][3], 0, 0, 0);
    }
    __syncthreads();  // protect Bs rewrite next iter

    if (it < 15) { v0 = t0; v1 = t1; v2 = t2; v3 = t3; }
  }

  // epilogue: D row=(lane>>4)*4+jj, col=lane&15 (per-fragment)
  const size_t ob =
      ((size_t)(bb * 512 + mt * 128 + wr * 64 + ((lane >> 4) << 2))) * 4096 +
      nt * 128 + wc * 64 + (lane & 15);
  #pragma unroll
  for (int mi = 0; mi < 4; ++mi)
    #pragma unroll
    for (int ni = 0; ni < 4; ++ni)
      #pragma unroll
      for (int jj = 0; jj < 4; ++jj)
        out[ob + (size_t)(mi * 16 + jj) * 4096 + ni * 16] = acc[mi][ni][jj];
}

extern "C" void kernel_launch(void* const* d_in, const int* in_sizes, int n_in,
                              void* d_out, int out_size, void* d_ws, size_t ws_size,
                              hipStream_t stream) {
  const float* x      = (const float*)d_in[0];
  const float* t      = (const float*)d_in[1];
  const float* weight = (const float*)d_in[2];
  const float* W1     = (const float*)d_in[3];
  const float* b1     = (const float*)d_in[4];
  const float* W2     = (const float*)d_in[5];
  const float* b2     = (const float*)d_in[6];
  const float* W3     = (const float*)d_in[7];
  const float* b3     = (const float*)d_in[8];
  float* out = (float*)d_out;

  float* s_ws = (float*)d_ws;                                   // 32 KB
  unsigned short* bwq = (unsigned short*)((char*)d_ws + 32 * 1024);  // 8 MB

  mlp_kernel<<<16, 256, 0, stream>>>(t, W1, b1, W2, b2, W3, b3, s_ws);
  modw_kernel<<<2048, 256, 0, stream>>>(weight, s_ws, bwq);
  gemm_kernel<<<2048, 256, 0, stream>>>(x, bwq, out);
}